// Round 10
// baseline (706.403 us; speedup 1.0000x reference)
//
#include <hip/hip_runtime.h>
#include <stdint.h>

// ---------------------------------------------------------------------------
// OneScaleMultiStepPredictor — MFMA bf16 implementation.
//
// R9 changes:
//  (a) child conv fully BRANCHLESS: all 27 k's straight-line, no __any.
//      Inactive k's load row 0 (L1 broadcast, ~free); 54 gathers issued
//      without control deps so the compiler can pipeline with counted vmcnt.
//      Evidence: R4-R9, every guarded variant pinned at 266-272 us; guarded
//      cross-k serial chains (~3.4 x 600-900 cy) were the per-wave floor.
//  (b) p1 GEMM split back out as a streaming kernel (sequential uq reads,
//      16x255 block writes) so the 408 MB output runs at streaming BW.
//  (c) child conv uses natural-m tiles (lists indirection dropped).
// ---------------------------------------------------------------------------

typedef short bf16x8 __attribute__((ext_vector_type(8)));
typedef float f32x4 __attribute__((ext_vector_type(4)));

#define EMPTY_KEY 0xFFFFFFFFu

__device__ __forceinline__ float rq(float x) {
  x *= (1.0f / 256.0f);
  return fminf(fmaxf(x, -128.0f), 127.0f);
}

__device__ __forceinline__ short f2b(float f) {  // fp32 -> bf16 (RNE)
  union { float f; uint32_t u; } v; v.f = f;
  uint32_t u = v.u;
  uint32_t r = (u + 0x7FFFu + ((u >> 16) & 1u)) >> 16;
  return (short)r;
}

__device__ __forceinline__ uint32_t hkey(int x, int y, int z) {
  return ((uint32_t)(x + 8) << 20) | ((uint32_t)(y + 8) << 10) | (uint32_t)(z + 8);
}
__device__ __forceinline__ uint32_t hfun(uint32_t key, uint32_t mask) {
  return (key * 2654435761u) & mask;
}

// ------------------------------ setup helpers ------------------------------

__device__ __forceinline__ void pack_conv_elem(const float* __restrict__ W,
                                               short* __restrict__ dst, int gid) {
  int lane = gid & 63;
  int c = (gid >> 6) & 3;
  int t = (gid >> 8) & 1;
  int k = gid >> 9;
  int n = c * 16 + (lane & 15);
  int g = lane >> 4;
  bf16x8 v;
#pragma unroll
  for (int e = 0; e < 8; e++) {
    int kk = t * 32 + g * 8 + e;
    v[e] = f2b(W[(k * 64 + kk) * 64 + n]);
  }
  *(bf16x8*)(dst + gid * 8) = v;
}

__device__ __forceinline__ void pack_dense_elem(const float* __restrict__ W,
                                                short* __restrict__ dst, int K,
                                                int Ncols, int KT, int CT, int gid) {
  if (gid >= KT * CT * 64) return;
  int lane = gid & 63;
  int c = (gid >> 6) % CT;
  int t = gid / (64 * CT);
  int n = c * 16 + (lane & 15);
  int g = lane >> 4;
  bf16x8 v;
#pragma unroll
  for (int e = 0; e < 8; e++) {
    int kk = t * 32 + g * 8 + e;
    float val = (kk < K && n < Ncols) ? W[kk * Ncols + n] : 0.0f;
    v[e] = f2b(val);
  }
  *(bf16x8*)(dst + gid * 8) = v;
}

struct SetupA {
  const float *dec_W, *p0_Wl, *p1_Wl, *res_W1, *res_W2, *p0_Wc, *p1_Wc;
  const int *bins1, *child_idx, *bins0;
  uint32_t* rkeys;
  short *wpack, *decwp, *p0wp, *p1wp;
  int *bitsPk, *pStart, *bcnt;
  float* outOct;
  int N, M;
};

// Role-dispatched independent setup: fill rkeys | pack convs | pack denses |
// pack_bits | parent_start | oct output | zero bcnt.
__global__ void __launch_bounds__(256) k_setupA(SetupA s) {
  int bid = blockIdx.x, tid = threadIdx.x;
  if (bid < 2048) {  // fill rkeys (HR = 2^19)
    s.rkeys[bid * 256 + tid] = EMPTY_KEY;
    return;
  }
  bid -= 2048;
  if (bid < 216) {   // 4 conv weight packs, 54 blocks each
    int which = bid / 54, sb = bid % 54;
    int gid = sb * 256 + tid;
    if (gid < 27 * 2 * 4 * 64) {
      const float* W = which == 0 ? s.res_W1 : which == 1 ? s.res_W2
                     : which == 2 ? s.p0_Wc : s.p1_Wc;
      pack_conv_elem(W, s.wpack + which * 110592, gid);
    }
    return;
  }
  bid -= 216;
  if (bid < 27) {    // dense packs: dec(3) | p0_Wl(16) | p1_Wl(8)
    if (bid < 3) pack_dense_elem(s.dec_W, s.decwp, 72, 64, 3, 4, bid * 256 + tid);
    else if (bid < 19) pack_dense_elem(s.p0_Wl, s.p0wp, 64, 512, 2, 32, (bid - 3) * 256 + tid);
    else pack_dense_elem(s.p1_Wl, s.p1wp, 64, 255, 2, 16, (bid - 19) * 256 + tid);
    return;
  }
  bid -= 27;
  int nbN = (s.N + 255) / 256, nbM = (s.M + 255) / 256;
  if (bid < nbN) {   // pack bins1 bits
    int p = bid * 256 + tid;
    if (p < s.N) {
      int b = 0;
#pragma unroll
      for (int e = 0; e < 8; e++) b |= (s.bins1[(size_t)p * 8 + e] & 1) << e;
      s.bitsPk[p] = b;
    }
    return;
  }
  bid -= nbN;
  if (bid < nbM) {   // parent start
    int m = bid * 256 + tid;
    if (m < s.M) {
      int p = s.child_idx[m] >> 3;
      if (m == 0 || (s.child_idx[m - 1] >> 3) != p) s.pStart[p] = m;
    }
    return;
  }
  bid -= nbM;
  if (bid < nbM) {   // oct output
    int m = bid * 256 + tid;
    if (m < s.M) {
      int ss = 0;
#pragma unroll
      for (int e = 0; e < 8; e++) ss += s.bins0[(size_t)m * 8 + e] << e;
      s.outOct[m] = (float)(ss - 1);
    }
    return;
  }
  if (tid < 8) s.bcnt[tid] = 0;
}

// hash_insert (rec) | hierarchical bucket.
__global__ void __launch_bounds__(256)
k_setupB(const int* __restrict__ rec_C, const int* __restrict__ child_idx,
         uint32_t* __restrict__ rkeys, int* __restrict__ rvals,
         int* __restrict__ lists, int* __restrict__ cnt, int N, int M) {
  int bid = blockIdx.x, tid = threadIdx.x;
  int nbN = (N + 255) / 256;
  if (bid < nbN) {
    int i = bid * 256 + tid;
    if (i >= N) return;
    uint32_t key = hkey(rec_C[i * 3], rec_C[i * 3 + 1], rec_C[i * 3 + 2]);
    uint32_t s = hfun(key, (1u << 19) - 1);
    while (true) {
      uint32_t old = atomicCAS(&rkeys[s], EMPTY_KEY, key);
      if (old == EMPTY_KEY) { rvals[s] = i; return; }
      s = (s + 1) & ((1u << 19) - 1);
    }
  }
  bid -= nbN;
  __shared__ int lcnt[8];
  __shared__ int lbase[8];
  if (tid < 8) lcnt[tid] = 0;
  __syncthreads();
  int m = bid * 256 + tid;
  int b = 0, lp = 0;
  if (m < M) {
    b = child_idx[m] & 7;
    lp = atomicAdd(&lcnt[b], 1);
  }
  __syncthreads();
  if (tid < 8) lbase[tid] = atomicAdd(&cnt[tid], lcnt[tid]);
  __syncthreads();
  if (m < M) lists[(size_t)b * M + lbase[b] + lp] = m;
}

// rec nbr build (hash), one thread per (i,k).
__global__ void __launch_bounds__(256)
k_setupC1(const int* __restrict__ rec_C,
          const uint32_t* __restrict__ rkeys, const int* __restrict__ rvals,
          int* __restrict__ nbrR, int N) {
  const uint32_t rmask = (1u << 19) - 1;
  int t = blockIdx.x * 256 + threadIdx.x;
  if (t >= N * 27) return;
  int i = t / 27, k = t % 27;
  int dx = k / 9 - 1, dy = (k / 3) % 3 - 1, dz = k % 3 - 1;
  int x = rec_C[i * 3] + dx * 2;
  int y = rec_C[i * 3 + 1] + dy * 2;
  int z = rec_C[i * 3 + 2] + dz * 2;
  uint32_t key = hkey(x, y, z);
  uint32_t s = hfun(key, rmask);
  int res = -1;
  while (true) {
    uint32_t kk = rkeys[s];
    if (kk == key) { res = rvals[s]; break; }
    if (kk == EMPTY_KEY) break;
    s = (s + 1) & rmask;
  }
  nbrR[(size_t)i * 28 + k] = res;
}

// child nbr build, one thread per child, NO hash: candidate parent rec-rows
// come from nbrR[parent_row][kk]; presence/rank from bins1 bits + pStart.
__global__ void __launch_bounds__(256)
k_setupC2(const int* __restrict__ child_C, const int* __restrict__ child_idx,
          const int* __restrict__ nbrR, const int* __restrict__ bitsPacked,
          const int* __restrict__ parentStart, int* __restrict__ nbrC, int M) {
  int m = blockIdx.x * 256 + threadIdx.x;
  if (m >= M) return;
  int cx = child_C[(size_t)m * 3], cy = child_C[(size_t)m * 3 + 1],
      cz = child_C[(size_t)m * 3 + 2];
  int pr = child_idx[m] >> 3;
  const int* nrow = nbrR + (size_t)pr * 28;
  int px = cx & 1, py = cy & 1, pz = cz & 1;

  int b8[8], s8[8];
#pragma unroll
  for (int j = 0; j < 8; j++) {
    int ddx = (px - 1) + ((j >> 2) & 1);
    int ddy = (py - 1) + ((j >> 1) & 1);
    int ddz = (pz - 1) + (j & 1);
    int kk = (ddx + 1) * 9 + (ddy + 1) * 3 + (ddz + 1);
    int r = nrow[kk];
    b8[j] = (r >= 0) ? bitsPacked[r] : 0;
    s8[j] = (r >= 0) ? parentStart[r] : 0;
  }

  int nout[28];
  nout[27] = -1;
#pragma unroll
  for (int k = 0; k < 27; k++) {
    const int dx = k / 9 - 1, dy = (k / 3) % 3 - 1, dz = k % 3 - 1;
    int tx = cx + dx, ty = cy + dy, tz = cz + dz;
    int jx = ((px + dx + 2) >> 1) - px;
    int jy = ((py + dy + 2) >> 1) - py;
    int jz = ((pz + dz + 2) >> 1) - pz;
    int j = jx * 4 + jy * 2 + jz;
    int bit = ((tx & 1) << 2) | ((ty & 1) << 1) | (tz & 1);
    int bits = b8[j];
    int res = -1;
    if ((bits >> bit) & 1) res = s8[j] + __popc(bits & ((1 << bit) - 1));
    nout[k] = res;
  }
#pragma unroll
  for (int q = 0; q < 7; q++)
    *(int4*)(nbrC + (size_t)m * 28 + q * 4) =
        make_int4(nout[q * 4], nout[q * 4 + 1], nout[q * 4 + 2], nout[q * 4 + 3]);
}

// ------------------------------ compute kernels ----------------------------

// dec: h = prelu(requant([rec_F | bins1]) @ dec_W + b, a); h32 + requant bf16
__global__ void __launch_bounds__(256)
k_dec(const float* __restrict__ recF, const int* __restrict__ bits,
      const short* __restrict__ wp, const float* __restrict__ bias,
      const float* __restrict__ alpha, float* __restrict__ h32,
      short* __restrict__ hq) {
  int tid = threadIdx.x, wid = tid >> 6, lane = tid & 63;
  int rowbase = blockIdx.x * 64 + wid * 16;
  int lrow = rowbase + (lane & 15);
  int g = lane >> 4;
  f32x4 acc[4] = {};
#pragma unroll
  for (int t = 0; t < 3; t++) {
    bf16x8 a = {0, 0, 0, 0, 0, 0, 0, 0};
    if (t < 2) {
      const float* src = recF + (size_t)lrow * 64 + t * 32 + g * 8;
#pragma unroll
      for (int e = 0; e < 8; e++) a[e] = f2b(rq(src[e]));
    } else if (g == 0) {
      const int* bp = bits + (size_t)lrow * 8;
#pragma unroll
      for (int e = 0; e < 8; e++) a[e] = f2b((float)bp[e]);
    }
#pragma unroll
    for (int c = 0; c < 4; c++) {
      bf16x8 b = *(const bf16x8*)(wp + ((t * 4 + c) * 64 + lane) * 8);
      acc[c] = __builtin_amdgcn_mfma_f32_16x16x32_bf16(a, b, acc[c], 0, 0, 0);
    }
  }
#pragma unroll
  for (int c = 0; c < 4; c++) {
    int col = c * 16 + (lane & 15);
    float bi = bias[col], al = alpha[col];
#pragma unroll
    for (int r = 0; r < 4; r++) {
      int row = rowbase + g * 4 + r;
      float v = acc[c][r] + bi;
      v = v >= 0.0f ? v : al * v;
      h32[(size_t)row * 64 + col] = v;
      hq[(size_t)row * 64 + col] = f2b(rq(v));
    }
  }
}

// 27-point gather conv. SKIP=true: wave-uniform __any skip per k (sparse rec
// graph). SKIP=false: fully branchless all-27 (child graph; inactive lanes
// read row 0 = L1 broadcast).
// MODE 0: outq = requant(prelu(acc+b, a)).
// MODE 1: out32 = resid + acc + b (to d_out); outq = requant(out32).
template <int MODE, bool SKIP>
__global__ void __launch_bounds__(256, 4)
k_conv(const short* __restrict__ fin, const int* __restrict__ nbr,
       const short* __restrict__ wp, const float* __restrict__ bias,
       const float* __restrict__ alpha, const float* __restrict__ resid,
       float* __restrict__ out32, short* __restrict__ outq) {
  int tid = threadIdx.x, wid = tid >> 6, lane = tid & 63;
  int rowbase = blockIdx.x * 64 + wid * 16;
  int lrow = rowbase + (lane & 15);
  int g = lane >> 4;

  int4 nv[7];
#pragma unroll
  for (int j = 0; j < 7; j++)
    nv[j] = *(const int4*)(nbr + (size_t)lrow * 28 + j * 4);
  int nbk[28];
#pragma unroll
  for (int j = 0; j < 7; j++) {
    nbk[j * 4 + 0] = nv[j].x;
    nbk[j * 4 + 1] = nv[j].y;
    nbk[j * 4 + 2] = nv[j].z;
    nbk[j * 4 + 3] = nv[j].w;
  }

  const bf16x8 zz = {0, 0, 0, 0, 0, 0, 0, 0};
  f32x4 acc[4] = {};
#pragma unroll
  for (int k = 0; k < 27; k++) {
    if (!SKIP || __any(nbk[k] >= 0)) {
      int nb = nbk[k];
      int safe = nb >= 0 ? nb : 0;
      const short* fp = fin + (size_t)safe * 64 + g * 8;
      bf16x8 a0 = *(const bf16x8*)fp;
      bf16x8 a1 = *(const bf16x8*)(fp + 32);
      a0 = nb >= 0 ? a0 : zz;
      a1 = nb >= 0 ? a1 : zz;
      const short* wk = wp + k * 4096;
#pragma unroll
      for (int c = 0; c < 4; c++) {
        bf16x8 b0 = *(const bf16x8*)(wk + (c * 64 + lane) * 8);
        acc[c] = __builtin_amdgcn_mfma_f32_16x16x32_bf16(a0, b0, acc[c], 0, 0, 0);
      }
#pragma unroll
      for (int c = 0; c < 4; c++) {
        bf16x8 b1 = *(const bf16x8*)(wk + ((4 + c) * 64 + lane) * 8);
        acc[c] = __builtin_amdgcn_mfma_f32_16x16x32_bf16(a1, b1, acc[c], 0, 0, 0);
      }
    }
  }
#pragma unroll
  for (int c = 0; c < 4; c++) {
    int col = c * 16 + (lane & 15);
    float bi = bias[col];
    float al = (MODE == 0) ? alpha[col] : 0.0f;
#pragma unroll
    for (int r = 0; r < 4; r++) {
      int row = rowbase + g * 4 + r;
      float v = acc[c][r] + bi;
      if (MODE == 0) {
        v = v >= 0.0f ? v : al * v;
        outq[(size_t)row * 64 + col] = f2b(rq(v));
      } else {
        v += resid[(size_t)row * 64 + col];
        out32[(size_t)row * 64 + col] = v;
        outq[(size_t)row * 64 + col] = f2b(rq(v));
      }
    }
  }
}

// Bucketed p0_Wl projection: tq[m] = requant(qq[parent(m)] @ p0_Wl[:, bit*64:+64])
__global__ void __launch_bounds__(256)
k_p0(const short* __restrict__ qq, const int* __restrict__ child_idx,
     const int* __restrict__ lists, const int* __restrict__ cnt,
     const short* __restrict__ wp, short* __restrict__ tq, int M) {
  int b = blockIdx.y;
  int cb = cnt[b];
  int start = blockIdx.x * 64;
  if (start >= cb) return;
  int tid = threadIdx.x, wid = tid >> 6, lane = tid & 63, g = lane >> 4;
  int posA = start + wid * 16 + (lane & 15);
  int parent = -1;
  if (posA < cb) parent = child_idx[lists[(size_t)b * M + posA]] >> 3;
  f32x4 acc[4] = {};
#pragma unroll
  for (int t = 0; t < 2; t++) {
    bf16x8 a = {0, 0, 0, 0, 0, 0, 0, 0};
    if (parent >= 0) a = *(const bf16x8*)(qq + (size_t)parent * 64 + t * 32 + g * 8);
#pragma unroll
    for (int c = 0; c < 4; c++) {
      bf16x8 bb = *(const bf16x8*)(wp + (((size_t)t * 32 + b * 4 + c) * 64 + lane) * 8);
      acc[c] = __builtin_amdgcn_mfma_f32_16x16x32_bf16(a, bb, acc[c], 0, 0, 0);
    }
  }
#pragma unroll
  for (int r = 0; r < 4; r++) {
    int posD = start + wid * 16 + g * 4 + r;
    if (posD < cb) {
      int m = lists[(size_t)b * M + posD];
#pragma unroll
      for (int c = 0; c < 4; c++) {
        int col = c * 16 + (lane & 15);
        tq[(size_t)m * 64 + col] = f2b(rq(acc[c][r]));
      }
    }
  }
}

// pred = uq @ p1_Wl (255 cols). Streaming: sequential uq reads, 16x255 block
// writes; 4 col-tile groups keep acc live-range at 16 regs.
__global__ void __launch_bounds__(256, 4)
k_p1(const short* __restrict__ uq, const short* __restrict__ p1wp,
     float* __restrict__ out) {
  int tid = threadIdx.x, wid = tid >> 6, lane = tid & 63;
  int l15 = lane & 15, g = lane >> 4;
  int rowbase = blockIdx.x * 64 + wid * 16;
  int lrow = rowbase + l15;
  bf16x8 a0 = *(const bf16x8*)(uq + (size_t)lrow * 64 + g * 8);
  bf16x8 a1 = *(const bf16x8*)(uq + (size_t)lrow * 64 + 32 + g * 8);
#pragma unroll
  for (int grp = 0; grp < 4; grp++) {
    f32x4 a2[4] = {};
#pragma unroll
    for (int c = 0; c < 4; c++) {
      bf16x8 b0 = *(const bf16x8*)(p1wp + ((grp * 4 + c) * 64 + lane) * 8);
      a2[c] = __builtin_amdgcn_mfma_f32_16x16x32_bf16(a0, b0, a2[c], 0, 0, 0);
      bf16x8 b1 = *(const bf16x8*)(p1wp + ((16 + grp * 4 + c) * 64 + lane) * 8);
      a2[c] = __builtin_amdgcn_mfma_f32_16x16x32_bf16(a1, b1, a2[c], 0, 0, 0);
    }
#pragma unroll
    for (int r = 0; r < 4; r++) {
      int row = rowbase + g * 4 + r;
#pragma unroll
      for (int c = 0; c < 4; c++) {
        int col = (grp * 4 + c) * 16 + l15;
        if (col < 255) out[(size_t)row * 255 + col] = a2[c][r];
      }
    }
  }
}

// ------------------------------ host launcher ------------------------------

extern "C" void kernel_launch(void* const* d_in, const int* in_sizes, int n_in,
                              void* d_out, int out_size, void* d_ws, size_t ws_size,
                              hipStream_t stream) {
  const float* rec_F  = (const float*)d_in[0];
  const float* dec_W  = (const float*)d_in[1];
  const float* dec_b  = (const float*)d_in[2];
  const float* dec_a  = (const float*)d_in[3];
  const float* res_W1 = (const float*)d_in[4];
  const float* res_b1 = (const float*)d_in[5];
  const float* res_a1 = (const float*)d_in[6];
  const float* res_W2 = (const float*)d_in[7];
  const float* res_b2 = (const float*)d_in[8];
  const float* p0_Wc  = (const float*)d_in[9];
  const float* p0_bc  = (const float*)d_in[10];
  const float* p0_ac  = (const float*)d_in[11];
  const float* p0_Wl  = (const float*)d_in[12];
  const float* p1_Wc  = (const float*)d_in[13];
  const float* p1_bc  = (const float*)d_in[14];
  const float* p1_ac  = (const float*)d_in[15];
  const float* p1_Wl  = (const float*)d_in[16];
  const int* rec_C    = (const int*)d_in[17];
  const int* bins1    = (const int*)d_in[18];
  const int* child_idx= (const int*)d_in[19];
  const int* child_C  = (const int*)d_in[20];
  const int* bins0    = (const int*)d_in[21];

  const int N = in_sizes[0] / 64;   // 200000
  const int M = in_sizes[19];       // 400000

  char* ws = (char*)d_ws;
  size_t off = 0;
  auto alloc = [&](size_t bytes) -> char* {
    char* p = ws + off;
    off += (bytes + 255) & ~(size_t)255;
    return p;
  };
  const uint32_t HR = 1u << 19;
  uint32_t* rkeys = (uint32_t*)alloc((size_t)HR * 4);
  int*      rvals = (int*)alloc((size_t)HR * 4);
  int* nbrR = (int*)alloc((size_t)N * 28 * 4);
  int* nbrC = (int*)alloc((size_t)M * 28 * 4);
  short* wpack = (short*)alloc((size_t)4 * 110592 * 2);
  short* decwp = (short*)alloc((size_t)3 * 4 * 64 * 8 * 2);
  short* p0wp  = (short*)alloc((size_t)2 * 32 * 64 * 8 * 2);
  short* p1wp  = (short*)alloc((size_t)2 * 16 * 64 * 8 * 2);
  short* bufA = (short*)alloc((size_t)N * 64 * 2);
  short* bufB = (short*)alloc((size_t)N * 64 * 2);
  float* h32  = (float*)alloc((size_t)N * 64 * 4);
  short* tq   = (short*)alloc((size_t)M * 64 * 2);
  short* uq   = (short*)alloc((size_t)M * 64 * 2);
  int* lists  = (int*)alloc((size_t)8 * M * 4);
  int* bcnt   = (int*)alloc(256);
  int* bitsPk = (int*)alloc((size_t)N * 4);
  int* pStart = (int*)alloc((size_t)N * 4);

  float* outRec  = (float*)d_out;
  float* outPred = outRec + (size_t)N * 64;
  float* outOct  = outPred + (size_t)M * 255;

  dim3 B(256);
  int nbN = (N + 255) / 256, nbM = (M + 255) / 256;

  // setup
  SetupA sa = {dec_W, p0_Wl, p1_Wl, res_W1, res_W2, p0_Wc, p1_Wc,
               bins1, child_idx, bins0, rkeys, wpack, decwp, p0wp, p1wp,
               bitsPk, pStart, bcnt, outOct, N, M};
  int gridA = 2048 + 216 + 27 + nbN + nbM + nbM + 1;
  k_setupA<<<gridA, B, 0, stream>>>(sa);
  k_setupB<<<nbN + nbM, B, 0, stream>>>(rec_C, child_idx, rkeys, rvals,
                                        lists, bcnt, N, M);
  k_setupC1<<<(N * 27 + 255) / 256, B, 0, stream>>>(rec_C, rkeys, rvals, nbrR, N);
  k_setupC2<<<nbM, B, 0, stream>>>(child_C, child_idx, nbrR, bitsPk, pStart,
                                   nbrC, M);

  // compute
  k_dec<<<N / 64, B, 0, stream>>>(rec_F, bins1, decwp, dec_b, dec_a, h32, bufA);
  k_conv<0, true><<<N / 64, B, 0, stream>>>(bufA, nbrR, wpack, res_b1, res_a1,
                                            nullptr, nullptr, bufB);
  k_conv<1, true><<<N / 64, B, 0, stream>>>(bufB, nbrR, wpack + 110592, res_b2,
                                            nullptr, h32, outRec, bufA);
  k_conv<0, true><<<N / 64, B, 0, stream>>>(bufA, nbrR, wpack + 221184, p0_bc,
                                            p0_ac, nullptr, nullptr, bufB);
  k_p0<<<dim3(M / 64, 8), B, 0, stream>>>(bufB, child_idx, lists, bcnt, p0wp, tq, M);
  k_conv<0, false><<<M / 64, B, 0, stream>>>(tq, nbrC, wpack + 331776, p1_bc,
                                             p1_ac, nullptr, nullptr, uq);
  k_p1<<<M / 64, B, 0, stream>>>(uq, p1wp, outPred);
}

// Round 11
// 602.848 us; speedup vs baseline: 1.1718x; 1.1718x over previous
//
#include <hip/hip_runtime.h>
#include <stdint.h>

// ---------------------------------------------------------------------------
// OneScaleMultiStepPredictor — MFMA bf16 implementation.
//
// R10 changes:
//  (a) REVERT R9 (branchless all-27 + split p1 regressed 620->706; __any skip
//      was saving ~30% of child-conv work, split re-added uq round-trip).
//      Back to R8: fused convp1, bucket-pure tiles, own-8 batch + guarded
//      cross-k.
//  (b) __builtin_amdgcn_sched_barrier(0) after the own-8 fragment loads:
//      R8 evidence VGPR=56 => compiler SANK the 16 batched loads back to
//      their uses, destroying MLP. The fence pins all 16 global_load_dwordx4
//      before the first MFMA.
// ---------------------------------------------------------------------------

typedef short bf16x8 __attribute__((ext_vector_type(8)));
typedef float f32x4 __attribute__((ext_vector_type(4)));

#define EMPTY_KEY 0xFFFFFFFFu

__device__ __forceinline__ float rq(float x) {
  x *= (1.0f / 256.0f);
  return fminf(fmaxf(x, -128.0f), 127.0f);
}

__device__ __forceinline__ short f2b(float f) {  // fp32 -> bf16 (RNE)
  union { float f; uint32_t u; } v; v.f = f;
  uint32_t u = v.u;
  uint32_t r = (u + 0x7FFFu + ((u >> 16) & 1u)) >> 16;
  return (short)r;
}

__device__ __forceinline__ uint32_t hkey(int x, int y, int z) {
  return ((uint32_t)(x + 8) << 20) | ((uint32_t)(y + 8) << 10) | (uint32_t)(z + 8);
}
__device__ __forceinline__ uint32_t hfun(uint32_t key, uint32_t mask) {
  return (key * 2654435761u) & mask;
}

// ------------------------------ setup helpers ------------------------------

__device__ __forceinline__ void pack_conv_elem(const float* __restrict__ W,
                                               short* __restrict__ dst, int gid) {
  int lane = gid & 63;
  int c = (gid >> 6) & 3;
  int t = (gid >> 8) & 1;
  int k = gid >> 9;
  int n = c * 16 + (lane & 15);
  int g = lane >> 4;
  bf16x8 v;
#pragma unroll
  for (int e = 0; e < 8; e++) {
    int kk = t * 32 + g * 8 + e;
    v[e] = f2b(W[(k * 64 + kk) * 64 + n]);
  }
  *(bf16x8*)(dst + gid * 8) = v;
}

__device__ __forceinline__ void pack_dense_elem(const float* __restrict__ W,
                                                short* __restrict__ dst, int K,
                                                int Ncols, int KT, int CT, int gid) {
  if (gid >= KT * CT * 64) return;
  int lane = gid & 63;
  int c = (gid >> 6) % CT;
  int t = gid / (64 * CT);
  int n = c * 16 + (lane & 15);
  int g = lane >> 4;
  bf16x8 v;
#pragma unroll
  for (int e = 0; e < 8; e++) {
    int kk = t * 32 + g * 8 + e;
    float val = (kk < K && n < Ncols) ? W[kk * Ncols + n] : 0.0f;
    v[e] = f2b(val);
  }
  *(bf16x8*)(dst + gid * 8) = v;
}

struct SetupA {
  const float *dec_W, *p0_Wl, *p1_Wl, *res_W1, *res_W2, *p0_Wc, *p1_Wc;
  const int *bins1, *child_idx, *bins0;
  uint32_t* rkeys;
  short *wpack, *decwp, *p0wp, *p1wp;
  int *bitsPk, *pStart, *bcnt;
  float* outOct;
  int N, M;
};

// Role-dispatched independent setup: fill rkeys | pack convs | pack denses |
// pack_bits | parent_start | oct output | zero bcnt.
__global__ void __launch_bounds__(256) k_setupA(SetupA s) {
  int bid = blockIdx.x, tid = threadIdx.x;
  if (bid < 2048) {  // fill rkeys (HR = 2^19)
    s.rkeys[bid * 256 + tid] = EMPTY_KEY;
    return;
  }
  bid -= 2048;
  if (bid < 216) {   // 4 conv weight packs, 54 blocks each
    int which = bid / 54, sb = bid % 54;
    int gid = sb * 256 + tid;
    if (gid < 27 * 2 * 4 * 64) {
      const float* W = which == 0 ? s.res_W1 : which == 1 ? s.res_W2
                     : which == 2 ? s.p0_Wc : s.p1_Wc;
      pack_conv_elem(W, s.wpack + which * 110592, gid);
    }
    return;
  }
  bid -= 216;
  if (bid < 27) {    // dense packs: dec(3) | p0_Wl(16) | p1_Wl(8)
    if (bid < 3) pack_dense_elem(s.dec_W, s.decwp, 72, 64, 3, 4, bid * 256 + tid);
    else if (bid < 19) pack_dense_elem(s.p0_Wl, s.p0wp, 64, 512, 2, 32, (bid - 3) * 256 + tid);
    else pack_dense_elem(s.p1_Wl, s.p1wp, 64, 255, 2, 16, (bid - 19) * 256 + tid);
    return;
  }
  bid -= 27;
  int nbN = (s.N + 255) / 256, nbM = (s.M + 255) / 256;
  if (bid < nbN) {   // pack bins1 bits
    int p = bid * 256 + tid;
    if (p < s.N) {
      int b = 0;
#pragma unroll
      for (int e = 0; e < 8; e++) b |= (s.bins1[(size_t)p * 8 + e] & 1) << e;
      s.bitsPk[p] = b;
    }
    return;
  }
  bid -= nbN;
  if (bid < nbM) {   // parent start
    int m = bid * 256 + tid;
    if (m < s.M) {
      int p = s.child_idx[m] >> 3;
      if (m == 0 || (s.child_idx[m - 1] >> 3) != p) s.pStart[p] = m;
    }
    return;
  }
  bid -= nbM;
  if (bid < nbM) {   // oct output
    int m = bid * 256 + tid;
    if (m < s.M) {
      int ss = 0;
#pragma unroll
      for (int e = 0; e < 8; e++) ss += s.bins0[(size_t)m * 8 + e] << e;
      s.outOct[m] = (float)(ss - 1);
    }
    return;
  }
  if (tid < 8) s.bcnt[tid] = 0;
}

// hash_insert (rec) | hierarchical bucket.
__global__ void __launch_bounds__(256)
k_setupB(const int* __restrict__ rec_C, const int* __restrict__ child_idx,
         uint32_t* __restrict__ rkeys, int* __restrict__ rvals,
         int* __restrict__ lists, int* __restrict__ cnt, int N, int M) {
  int bid = blockIdx.x, tid = threadIdx.x;
  int nbN = (N + 255) / 256;
  if (bid < nbN) {
    int i = bid * 256 + tid;
    if (i >= N) return;
    uint32_t key = hkey(rec_C[i * 3], rec_C[i * 3 + 1], rec_C[i * 3 + 2]);
    uint32_t s = hfun(key, (1u << 19) - 1);
    while (true) {
      uint32_t old = atomicCAS(&rkeys[s], EMPTY_KEY, key);
      if (old == EMPTY_KEY) { rvals[s] = i; return; }
      s = (s + 1) & ((1u << 19) - 1);
    }
  }
  bid -= nbN;
  __shared__ int lcnt[8];
  __shared__ int lbase[8];
  if (tid < 8) lcnt[tid] = 0;
  __syncthreads();
  int m = bid * 256 + tid;
  int b = 0, lp = 0;
  if (m < M) {
    b = child_idx[m] & 7;
    lp = atomicAdd(&lcnt[b], 1);
  }
  __syncthreads();
  if (tid < 8) lbase[tid] = atomicAdd(&cnt[tid], lcnt[tid]);
  __syncthreads();
  if (m < M) lists[(size_t)b * M + lbase[b] + lp] = m;
}

// rec nbr build (hash), one thread per (i,k).
__global__ void __launch_bounds__(256)
k_setupC1(const int* __restrict__ rec_C,
          const uint32_t* __restrict__ rkeys, const int* __restrict__ rvals,
          int* __restrict__ nbrR, int N) {
  const uint32_t rmask = (1u << 19) - 1;
  int t = blockIdx.x * 256 + threadIdx.x;
  if (t >= N * 27) return;
  int i = t / 27, k = t % 27;
  int dx = k / 9 - 1, dy = (k / 3) % 3 - 1, dz = k % 3 - 1;
  int x = rec_C[i * 3] + dx * 2;
  int y = rec_C[i * 3 + 1] + dy * 2;
  int z = rec_C[i * 3 + 2] + dz * 2;
  uint32_t key = hkey(x, y, z);
  uint32_t s = hfun(key, rmask);
  int res = -1;
  while (true) {
    uint32_t kk = rkeys[s];
    if (kk == key) { res = rvals[s]; break; }
    if (kk == EMPTY_KEY) break;
    s = (s + 1) & rmask;
  }
  nbrR[(size_t)i * 28 + k] = res;
}

// child nbr build, one thread per child, NO hash: candidate parent rec-rows
// come from nbrR[parent_row][kk]; presence/rank from bins1 bits + pStart.
__global__ void __launch_bounds__(256)
k_setupC2(const int* __restrict__ child_C, const int* __restrict__ child_idx,
          const int* __restrict__ nbrR, const int* __restrict__ bitsPacked,
          const int* __restrict__ parentStart, int* __restrict__ nbrC, int M) {
  int m = blockIdx.x * 256 + threadIdx.x;
  if (m >= M) return;
  int cx = child_C[(size_t)m * 3], cy = child_C[(size_t)m * 3 + 1],
      cz = child_C[(size_t)m * 3 + 2];
  int pr = child_idx[m] >> 3;
  const int* nrow = nbrR + (size_t)pr * 28;
  int px = cx & 1, py = cy & 1, pz = cz & 1;

  int b8[8], s8[8];
#pragma unroll
  for (int j = 0; j < 8; j++) {
    int ddx = (px - 1) + ((j >> 2) & 1);
    int ddy = (py - 1) + ((j >> 1) & 1);
    int ddz = (pz - 1) + (j & 1);
    int kk = (ddx + 1) * 9 + (ddy + 1) * 3 + (ddz + 1);
    int r = nrow[kk];
    b8[j] = (r >= 0) ? bitsPacked[r] : 0;
    s8[j] = (r >= 0) ? parentStart[r] : 0;
  }

  int nout[28];
  nout[27] = -1;
#pragma unroll
  for (int k = 0; k < 27; k++) {
    const int dx = k / 9 - 1, dy = (k / 3) % 3 - 1, dz = k % 3 - 1;
    int tx = cx + dx, ty = cy + dy, tz = cz + dz;
    int jx = ((px + dx + 2) >> 1) - px;
    int jy = ((py + dy + 2) >> 1) - py;
    int jz = ((pz + dz + 2) >> 1) - pz;
    int j = jx * 4 + jy * 2 + jz;
    int bit = ((tx & 1) << 2) | ((ty & 1) << 1) | (tz & 1);
    int bits = b8[j];
    int res = -1;
    if ((bits >> bit) & 1) res = s8[j] + __popc(bits & ((1 << bit) - 1));
    nout[k] = res;
  }
#pragma unroll
  for (int q = 0; q < 7; q++)
    *(int4*)(nbrC + (size_t)m * 28 + q * 4) =
        make_int4(nout[q * 4], nout[q * 4 + 1], nout[q * 4 + 2], nout[q * 4 + 3]);
}

// ------------------------------ compute kernels ----------------------------

// dec: h = prelu(requant([rec_F | bins1]) @ dec_W + b, a); h32 + requant bf16
__global__ void __launch_bounds__(256)
k_dec(const float* __restrict__ recF, const int* __restrict__ bits,
      const short* __restrict__ wp, const float* __restrict__ bias,
      const float* __restrict__ alpha, float* __restrict__ h32,
      short* __restrict__ hq) {
  int tid = threadIdx.x, wid = tid >> 6, lane = tid & 63;
  int rowbase = blockIdx.x * 64 + wid * 16;
  int lrow = rowbase + (lane & 15);
  int g = lane >> 4;
  f32x4 acc[4] = {};
#pragma unroll
  for (int t = 0; t < 3; t++) {
    bf16x8 a = {0, 0, 0, 0, 0, 0, 0, 0};
    if (t < 2) {
      const float* src = recF + (size_t)lrow * 64 + t * 32 + g * 8;
#pragma unroll
      for (int e = 0; e < 8; e++) a[e] = f2b(rq(src[e]));
    } else if (g == 0) {
      const int* bp = bits + (size_t)lrow * 8;
#pragma unroll
      for (int e = 0; e < 8; e++) a[e] = f2b((float)bp[e]);
    }
#pragma unroll
    for (int c = 0; c < 4; c++) {
      bf16x8 b = *(const bf16x8*)(wp + ((t * 4 + c) * 64 + lane) * 8);
      acc[c] = __builtin_amdgcn_mfma_f32_16x16x32_bf16(a, b, acc[c], 0, 0, 0);
    }
  }
#pragma unroll
  for (int c = 0; c < 4; c++) {
    int col = c * 16 + (lane & 15);
    float bi = bias[col], al = alpha[col];
#pragma unroll
    for (int r = 0; r < 4; r++) {
      int row = rowbase + g * 4 + r;
      float v = acc[c][r] + bi;
      v = v >= 0.0f ? v : al * v;
      h32[(size_t)row * 64 + col] = v;
      hq[(size_t)row * 64 + col] = f2b(rq(v));
    }
  }
}

// 27-point gather conv (rec graph): unrolled 27-k + __any skip + branchless
// per-lane gather.
template <int MODE>
__global__ void __launch_bounds__(256)
k_conv(const short* __restrict__ fin, const int* __restrict__ nbr,
       const short* __restrict__ wp, const float* __restrict__ bias,
       const float* __restrict__ alpha, const float* __restrict__ resid,
       float* __restrict__ out32, short* __restrict__ outq) {
  int tid = threadIdx.x, wid = tid >> 6, lane = tid & 63;
  int rowbase = blockIdx.x * 64 + wid * 16;
  int lrow = rowbase + (lane & 15);
  int g = lane >> 4;

  int4 nv[7];
#pragma unroll
  for (int j = 0; j < 7; j++)
    nv[j] = *(const int4*)(nbr + (size_t)lrow * 28 + j * 4);
  int nbk[28];
#pragma unroll
  for (int j = 0; j < 7; j++) {
    nbk[j * 4 + 0] = nv[j].x;
    nbk[j * 4 + 1] = nv[j].y;
    nbk[j * 4 + 2] = nv[j].z;
    nbk[j * 4 + 3] = nv[j].w;
  }

  const bf16x8 zz = {0, 0, 0, 0, 0, 0, 0, 0};
  f32x4 acc[4] = {};
#pragma unroll
  for (int k = 0; k < 27; k++) {
    if (__any(nbk[k] >= 0)) {
      int nb = nbk[k];
      int safe = nb >= 0 ? nb : 0;
      const short* fp = fin + (size_t)safe * 64 + g * 8;
      bf16x8 a0 = *(const bf16x8*)fp;
      bf16x8 a1 = *(const bf16x8*)(fp + 32);
      a0 = nb >= 0 ? a0 : zz;
      a1 = nb >= 0 ? a1 : zz;
      const short* wk = wp + k * 4096;
#pragma unroll
      for (int c = 0; c < 4; c++) {
        bf16x8 b0 = *(const bf16x8*)(wk + (c * 64 + lane) * 8);
        acc[c] = __builtin_amdgcn_mfma_f32_16x16x32_bf16(a0, b0, acc[c], 0, 0, 0);
      }
#pragma unroll
      for (int c = 0; c < 4; c++) {
        bf16x8 b1 = *(const bf16x8*)(wk + ((4 + c) * 64 + lane) * 8);
        acc[c] = __builtin_amdgcn_mfma_f32_16x16x32_bf16(a1, b1, acc[c], 0, 0, 0);
      }
    }
  }
#pragma unroll
  for (int c = 0; c < 4; c++) {
    int col = c * 16 + (lane & 15);
    float bi = bias[col];
    float al = (MODE == 0) ? alpha[col] : 0.0f;
#pragma unroll
    for (int r = 0; r < 4; r++) {
      int row = rowbase + g * 4 + r;
      float v = acc[c][r] + bi;
      if (MODE == 0) {
        v = v >= 0.0f ? v : al * v;
        outq[(size_t)row * 64 + col] = f2b(rq(v));
      } else {
        v += resid[(size_t)row * 64 + col];
        out32[(size_t)row * 64 + col] = v;
        outq[(size_t)row * 64 + col] = f2b(rq(v));
      }
    }
  }
}

// Bucketed p0_Wl projection: tq[m] = requant(qq[parent(m)] @ p0_Wl[:, bit*64:+64])
__global__ void __launch_bounds__(256)
k_p0(const short* __restrict__ qq, const int* __restrict__ child_idx,
     const int* __restrict__ lists, const int* __restrict__ cnt,
     const short* __restrict__ wp, short* __restrict__ tq, int M) {
  int b = blockIdx.y;
  int cb = cnt[b];
  int start = blockIdx.x * 64;
  if (start >= cb) return;
  int tid = threadIdx.x, wid = tid >> 6, lane = tid & 63, g = lane >> 4;
  int posA = start + wid * 16 + (lane & 15);
  int parent = -1;
  if (posA < cb) parent = child_idx[lists[(size_t)b * M + posA]] >> 3;
  f32x4 acc[4] = {};
#pragma unroll
  for (int t = 0; t < 2; t++) {
    bf16x8 a = {0, 0, 0, 0, 0, 0, 0, 0};
    if (parent >= 0) a = *(const bf16x8*)(qq + (size_t)parent * 64 + t * 32 + g * 8);
#pragma unroll
    for (int c = 0; c < 4; c++) {
      bf16x8 bb = *(const bf16x8*)(wp + (((size_t)t * 32 + b * 4 + c) * 64 + lane) * 8);
      acc[c] = __builtin_amdgcn_mfma_f32_16x16x32_bf16(a, bb, acc[c], 0, 0, 0);
    }
  }
#pragma unroll
  for (int r = 0; r < 4; r++) {
    int posD = start + wid * 16 + g * 4 + r;
    if (posD < cb) {
      int m = lists[(size_t)b * M + posD];
#pragma unroll
      for (int c = 0; c < 4; c++) {
        int col = c * 16 + (lane & 15);
        tq[(size_t)m * 64 + col] = f2b(rq(acc[c][r]));
      }
    }
  }
}

// Fused child conv + p1 GEMM. Bucket-pure tiles: grid (M/64, 8). Own-8 k's
// branch-free with all 16 gathers pinned in flight via sched_barrier(0);
// cross k's guarded.
__global__ void __launch_bounds__(256, 4)
k_convp1(const short* __restrict__ fin, const int* __restrict__ nbr,
         const short* __restrict__ wp, const float* __restrict__ bias,
         const float* __restrict__ alpha,
         const int* __restrict__ lists, const int* __restrict__ cnt,
         const short* __restrict__ p1wp, float* __restrict__ out, int M) {
  __shared__ short lds[4][16][64];   // per-wave 16x64 bf16 tile, XOR-swizzled
  __shared__ int mrow[4][16];
  int b = blockIdx.y;
  int cb = cnt[b];
  int start = blockIdx.x * 64;
  if (start >= cb) return;
  int tid = threadIdx.x, wid = tid >> 6, lane = tid & 63;
  int l15 = lane & 15, g = lane >> 4;

  int pos = start + wid * 16 + l15;
  int m = (pos < cb) ? lists[(size_t)b * M + pos] : -1;
  if (g == 0) mrow[wid][l15] = m;

  int msafe = m >= 0 ? m : 0;
  const int* nrow = nbr + (size_t)msafe * 28;

  // own-parent k set (wave-uniform; b uniform per block)
  int px = (b >> 2) & 1, py = (b >> 1) & 1, pz = b & 1;
  int kown[8];
  uint32_t ownMask = 0;
#pragma unroll
  for (int j = 0; j < 8; j++) {
    int k = (((j >> 2) & 1) - px + 1) * 9 + (((j >> 1) & 1) - py + 1) * 3 +
            ((j & 1) - pz + 1);
    kown[j] = k;
    ownMask |= 1u << k;
  }

  // issue own nb loads + neighbor-row prefetch together
  int nbo[8];
#pragma unroll
  for (int j = 0; j < 8; j++) nbo[j] = nrow[kown[j]];
  int4 nv[7];
#pragma unroll
  for (int j = 0; j < 7; j++) nv[j] = *(const int4*)(nrow + j * 4);
  __builtin_amdgcn_sched_barrier(0);   // pin index loads before fragment loads

  const bf16x8 zz = {0, 0, 0, 0, 0, 0, 0, 0};

  // own-8 phase: ALL 16 fragment gathers issued, then FENCED so the compiler
  // cannot sink them to their uses (R8: it did, VGPR 56, serial chains).
  bf16x8 A0[8], A1[8];
#pragma unroll
  for (int j = 0; j < 8; j++) {
    int nb = (m >= 0) ? nbo[j] : -1;
    int safe = nb >= 0 ? nb : 0;
    const short* fp = fin + (size_t)safe * 64 + g * 8;
    bf16x8 x0 = *(const bf16x8*)fp;
    bf16x8 x1 = *(const bf16x8*)(fp + 32);
    A0[j] = nb >= 0 ? x0 : zz;
    A1[j] = nb >= 0 ? x1 : zz;
  }
  __builtin_amdgcn_sched_barrier(0);   // all 16 loads issued before any MFMA

  f32x4 acc[4] = {};
#pragma unroll
  for (int j = 0; j < 8; j++) {
    const short* wk = wp + kown[j] * 4096;
#pragma unroll
    for (int c = 0; c < 4; c++) {
      bf16x8 b0 = *(const bf16x8*)(wk + (c * 64 + lane) * 8);
      acc[c] = __builtin_amdgcn_mfma_f32_16x16x32_bf16(A0[j], b0, acc[c], 0, 0, 0);
    }
#pragma unroll
    for (int c = 0; c < 4; c++) {
      bf16x8 b1 = *(const bf16x8*)(wk + ((4 + c) * 64 + lane) * 8);
      acc[c] = __builtin_amdgcn_mfma_f32_16x16x32_bf16(A1[j], b1, acc[c], 0, 0, 0);
    }
  }

  // cross-parent k's (sparse): guarded serial path
  int nbk[28];
#pragma unroll
  for (int j = 0; j < 7; j++) {
    nbk[j * 4 + 0] = m >= 0 ? nv[j].x : -1;
    nbk[j * 4 + 1] = m >= 0 ? nv[j].y : -1;
    nbk[j * 4 + 2] = m >= 0 ? nv[j].z : -1;
    nbk[j * 4 + 3] = m >= 0 ? nv[j].w : -1;
  }
#pragma unroll
  for (int k = 0; k < 27; k++) {
    if (!((ownMask >> k) & 1) && __any(nbk[k] >= 0)) {
      int nb = nbk[k];
      int safe = nb >= 0 ? nb : 0;
      const short* fp = fin + (size_t)safe * 64 + g * 8;
      bf16x8 a0 = *(const bf16x8*)fp;
      bf16x8 a1 = *(const bf16x8*)(fp + 32);
      a0 = nb >= 0 ? a0 : zz;
      a1 = nb >= 0 ? a1 : zz;
      const short* wk = wp + k * 4096;
#pragma unroll
      for (int c = 0; c < 4; c++) {
        bf16x8 b0 = *(const bf16x8*)(wk + (c * 64 + lane) * 8);
        acc[c] = __builtin_amdgcn_mfma_f32_16x16x32_bf16(a0, b0, acc[c], 0, 0, 0);
      }
#pragma unroll
      for (int c = 0; c < 4; c++) {
        bf16x8 b1 = *(const bf16x8*)(wk + ((4 + c) * 64 + lane) * 8);
        acc[c] = __builtin_amdgcn_mfma_f32_16x16x32_bf16(a1, b1, acc[c], 0, 0, 0);
      }
    }
  }

  // uq = requant(prelu(acc+b, a)) -> LDS (XOR-swizzled, 8-short blocks).
#pragma unroll
  for (int c = 0; c < 4; c++) {
    int col = c * 16 + l15;
    float bi = bias[col], al = alpha[col];
#pragma unroll
    for (int r = 0; r < 4; r++) {
      int rowW = g * 4 + r;
      float v = acc[c][r] + bi;
      v = v >= 0.0f ? v : al * v;
      lds[wid][rowW][col ^ ((rowW & 7) << 3)] = f2b(rq(v));
    }
  }
  __syncthreads();

  bf16x8 a0 = *(const bf16x8*)&lds[wid][l15][(g * 8) ^ ((l15 & 7) << 3)];
  bf16x8 a1 = *(const bf16x8*)&lds[wid][l15][(32 + g * 8) ^ ((l15 & 7) << 3)];
#pragma unroll
  for (int grp = 0; grp < 4; grp++) {
    f32x4 a2[4] = {};
#pragma unroll
    for (int c = 0; c < 4; c++) {
      bf16x8 b0 = *(const bf16x8*)(p1wp + ((grp * 4 + c) * 64 + lane) * 8);
      a2[c] = __builtin_amdgcn_mfma_f32_16x16x32_bf16(a0, b0, a2[c], 0, 0, 0);
      bf16x8 b1 = *(const bf16x8*)(p1wp + ((16 + grp * 4 + c) * 64 + lane) * 8);
      a2[c] = __builtin_amdgcn_mfma_f32_16x16x32_bf16(a1, b1, a2[c], 0, 0, 0);
    }
#pragma unroll
    for (int r = 0; r < 4; r++) {
      int mo = mrow[wid][g * 4 + r];
      if (mo >= 0) {
#pragma unroll
        for (int c = 0; c < 4; c++) {
          int col = (grp * 4 + c) * 16 + l15;
          if (col < 255) out[(size_t)mo * 255 + col] = a2[c][r];
        }
      }
    }
  }
}

// ------------------------------ host launcher ------------------------------

extern "C" void kernel_launch(void* const* d_in, const int* in_sizes, int n_in,
                              void* d_out, int out_size, void* d_ws, size_t ws_size,
                              hipStream_t stream) {
  const float* rec_F  = (const float*)d_in[0];
  const float* dec_W  = (const float*)d_in[1];
  const float* dec_b  = (const float*)d_in[2];
  const float* dec_a  = (const float*)d_in[3];
  const float* res_W1 = (const float*)d_in[4];
  const float* res_b1 = (const float*)d_in[5];
  const float* res_a1 = (const float*)d_in[6];
  const float* res_W2 = (const float*)d_in[7];
  const float* res_b2 = (const float*)d_in[8];
  const float* p0_Wc  = (const float*)d_in[9];
  const float* p0_bc  = (const float*)d_in[10];
  const float* p0_ac  = (const float*)d_in[11];
  const float* p0_Wl  = (const float*)d_in[12];
  const float* p1_Wc  = (const float*)d_in[13];
  const float* p1_bc  = (const float*)d_in[14];
  const float* p1_ac  = (const float*)d_in[15];
  const float* p1_Wl  = (const float*)d_in[16];
  const int* rec_C    = (const int*)d_in[17];
  const int* bins1    = (const int*)d_in[18];
  const int* child_idx= (const int*)d_in[19];
  const int* child_C  = (const int*)d_in[20];
  const int* bins0    = (const int*)d_in[21];

  const int N = in_sizes[0] / 64;   // 200000
  const int M = in_sizes[19];       // 400000

  char* ws = (char*)d_ws;
  size_t off = 0;
  auto alloc = [&](size_t bytes) -> char* {
    char* p = ws + off;
    off += (bytes + 255) & ~(size_t)255;
    return p;
  };
  const uint32_t HR = 1u << 19;
  uint32_t* rkeys = (uint32_t*)alloc((size_t)HR * 4);
  int*      rvals = (int*)alloc((size_t)HR * 4);
  int* nbrR = (int*)alloc((size_t)N * 28 * 4);
  int* nbrC = (int*)alloc((size_t)M * 28 * 4);
  short* wpack = (short*)alloc((size_t)4 * 110592 * 2);
  short* decwp = (short*)alloc((size_t)3 * 4 * 64 * 8 * 2);
  short* p0wp  = (short*)alloc((size_t)2 * 32 * 64 * 8 * 2);
  short* p1wp  = (short*)alloc((size_t)2 * 16 * 64 * 8 * 2);
  short* bufA = (short*)alloc((size_t)N * 64 * 2);
  short* bufB = (short*)alloc((size_t)N * 64 * 2);
  float* h32  = (float*)alloc((size_t)N * 64 * 4);
  short* tq   = (short*)alloc((size_t)M * 64 * 2);
  int* lists  = (int*)alloc((size_t)8 * M * 4);
  int* bcnt   = (int*)alloc(256);
  int* bitsPk = (int*)alloc((size_t)N * 4);
  int* pStart = (int*)alloc((size_t)N * 4);

  float* outRec  = (float*)d_out;
  float* outPred = outRec + (size_t)N * 64;
  float* outOct  = outPred + (size_t)M * 255;

  dim3 B(256);
  int nbN = (N + 255) / 256, nbM = (M + 255) / 256;

  // setup
  SetupA sa = {dec_W, p0_Wl, p1_Wl, res_W1, res_W2, p0_Wc, p1_Wc,
               bins1, child_idx, bins0, rkeys, wpack, decwp, p0wp, p1wp,
               bitsPk, pStart, bcnt, outOct, N, M};
  int gridA = 2048 + 216 + 27 + nbN + nbM + nbM + 1;
  k_setupA<<<gridA, B, 0, stream>>>(sa);
  k_setupB<<<nbN + nbM, B, 0, stream>>>(rec_C, child_idx, rkeys, rvals,
                                        lists, bcnt, N, M);
  k_setupC1<<<(N * 27 + 255) / 256, B, 0, stream>>>(rec_C, rkeys, rvals, nbrR, N);
  k_setupC2<<<nbM, B, 0, stream>>>(child_C, child_idx, nbrR, bitsPk, pStart,
                                   nbrC, M);

  // compute
  k_dec<<<N / 64, B, 0, stream>>>(rec_F, bins1, decwp, dec_b, dec_a, h32, bufA);
  k_conv<0><<<N / 64, B, 0, stream>>>(bufA, nbrR, wpack, res_b1, res_a1,
                                      nullptr, nullptr, bufB);
  k_conv<1><<<N / 64, B, 0, stream>>>(bufB, nbrR, wpack + 110592, res_b2, nullptr,
                                      h32, outRec, bufA);
  k_conv<0><<<N / 64, B, 0, stream>>>(bufA, nbrR, wpack + 221184, p0_bc, p0_ac,
                                      nullptr, nullptr, bufB);
  k_p0<<<dim3(M / 64, 8), B, 0, stream>>>(bufB, child_idx, lists, bcnt, p0wp, tq, M);
  k_convp1<<<dim3((M + 63) / 64, 8), B, 0, stream>>>(
      tq, nbrC, wpack + 331776, p1_bc, p1_ac, lists, bcnt, p1wp, outPred, M);
}